// Round 14
// baseline (244.472 us; speedup 1.0000x reference)
//
#include <hip/hip_runtime.h>
#include <hip/hip_bf16.h>

#define N_NODES 100000
#define N_EDGES 1600000
#define FIN 512
#define FHID 128
#define FOUT 40
#define FOUTP 48                // FOUT padded to 3x16 for MFMA

#define SCAN_NB ((N_NODES + 255) / 256)   // 391 blocks, 1 node/thread

#define GH 64                   // edge slices
#define EDGE_SLICE (N_EDGES / GH)   // 25000

// histogram geometry: u16-packed pairs, 100KB LDS -> 2 ranges of 50000 nodes
#define NR2 2
#define RANGE2 50000
#define R2W 25000               // u32 words per range (100KB)
#define NHIST (2 * NR2 * GH)    // 256 histogram blocks

// scatter geometry: u32 cursors, 50KB LDS -> 8 ranges of 12500 nodes
// (50KB so the merged scatter+gemm1 kernel keeps gemm1 at 3 blocks/CU)
#define NRS 8
#define RS 12500
#define NSC (NRS * GH)          // 512 scatter blocks

typedef __attribute__((ext_vector_type(8))) short short8;   // 8 bf16 (4 VGPR)
typedef __attribute__((ext_vector_type(4))) float f32x4;    // MFMA acc

static __device__ inline unsigned short f2bf(float f) {     // cold paths only
    unsigned x = __float_as_uint(f);
    unsigned r = (x + 0x7fffu + ((x >> 16) & 1u)) >> 16;    // RNE
    return (unsigned short)r;
}

// hot-path pair conversion -> v_cvt_pk_bf16_f32 (compiler-emitted)
static __device__ inline unsigned pk2bf(float lo, float hi) {
    __hip_bfloat162 h = __float22bfloat162_rn(make_float2(lo, hi));
    return *(unsigned*)&h;
}
static __device__ inline unsigned short bf1(float f) {
    __hip_bfloat16 h = __float2bfloat16(f);
    return *(unsigned short*)&h;
}

// async global->LDS 16B copy: LDS dest = wave-uniform base + lane*16 (linear);
// swizzling achieved by pre-swizzling the per-lane GLOBAL source address.
static __device__ inline void gload_lds16(const unsigned short* g, unsigned short* l) {
    __builtin_amdgcn_global_load_lds(
        (const __attribute__((address_space(1))) unsigned int*)(g),
        (__attribute__((address_space(3))) unsigned int*)(l), 16, 0, 0);
}

// ---------------- hist_wcvt: u16-packed 100KB-LDS degree histograms + weight cvt ----
__global__ __launch_bounds__(256) void hist_wcvt(const int* __restrict__ src,
                                                 const int* __restrict__ dst,
                                                 unsigned* __restrict__ count2,
                                                 const float* __restrict__ W1,
                                                 const float* __restrict__ W2,
                                                 unsigned short* __restrict__ Wt,
                                                 unsigned short* __restrict__ W2t) {
    __shared__ unsigned hist[R2W];   // 100KB
    if (blockIdx.x >= NHIST) {
        int j = (blockIdx.x - NHIST) * 256 + threadIdx.x;
        if (j < FIN * FHID) {             // Wt[n][k] = bf16(W1[k][n]); j = k*128+n
            int k = j >> 7;
            int n = j & 127;
            Wt[n * FIN + k] = f2bf(W1[j]);
        } else if (j < FIN * FHID + FOUTP * FHID) {
            int jj = j - FIN * FHID;      // W2t[n][k]; jj = n*128+k
            int n = jj >> 7;
            int k = jj & 127;
            W2t[jj] = (n < FOUT) ? f2bf(W2[k * FOUT + n]) : (unsigned short)0;
        }
        return;
    }
    const int task = blockIdx.x / GH;
    const int g = blockIdx.x % GH;
    const int a = task / NR2;
    const int rg = task % NR2;
    const int lo = rg * RANGE2;
    const int t = threadIdx.x;
    for (int i = t; i < R2W; i += 256) hist[i] = 0;
    __syncthreads();
    const int* arr = a ? dst : src;
    const int4* p = (const int4*)(arr + g * EDGE_SLICE);
    for (int i = t; i < EDGE_SLICE / 4; i += 256) {
        int4 v = p[i];
        int x;
        x = v.x - lo; if ((unsigned)x < RANGE2) atomicAdd(&hist[x >> 1], 1u << ((x & 1) << 4));
        x = v.y - lo; if ((unsigned)x < RANGE2) atomicAdd(&hist[x >> 1], 1u << ((x & 1) << 4));
        x = v.z - lo; if ((unsigned)x < RANGE2) atomicAdd(&hist[x >> 1], 1u << ((x & 1) << 4));
        x = v.w - lo; if ((unsigned)x < RANGE2) atomicAdd(&hist[x >> 1], 1u << ((x & 1) << 4));
    }
    __syncthreads();
    unsigned* out = count2 + ((size_t)task * GH + g) * R2W;
    for (int i = t; i < R2W; i += 256) out[i] = hist[i];
}

// ---------------- deg_reduce_scan: norms + per-256-chunk degree sums ----------------
__global__ __launch_bounds__(256) void deg_reduce_scan(const unsigned* __restrict__ count2,
                                                       float* __restrict__ nsrc,
                                                       float* __restrict__ ndst,
                                                       unsigned* __restrict__ bsum) {
    __shared__ unsigned red[256];
    const int b = blockIdx.x, t = threadIdx.x;
    const int node = b * 256 + t;
    unsigned si = 0;
    if (node < N_NODES) {
        const int rg2 = node / RANGE2;
        const int wo = (node % RANGE2) >> 1;
        const int sh = (node & 1) << 4;
        const unsigned* ps = count2 + ((size_t)rg2 * GH) * R2W + wo;
        const unsigned* pd = count2 + ((size_t)(NR2 + rg2) * GH) * R2W + wo;
        unsigned so = 0;
        for (int g = 0; g < GH; g++) {
            so += (ps[(size_t)g * R2W] >> sh) & 0xffffu;
            si += (pd[(size_t)g * R2W] >> sh) & 0xffffu;
        }
        nsrc[node] = rsqrtf((float)(so < 1u ? 1u : so));
        ndst[node] = rsqrtf((float)(si < 1u ? 1u : si));
    }
    red[t] = si; __syncthreads();
    for (int off = 128; off > 0; off >>= 1) {
        if (t < off) red[t] += red[t + off];
        __syncthreads();
    }
    if (t == 0) bsum[b] = red[0];
}

// ---------------- scan_write_mk: bsum-prefix + rowptr + u32 scatter bases (fused) ----
__global__ __launch_bounds__(256) void scan_write_mk(const unsigned* __restrict__ count2,
                                                     const unsigned* __restrict__ bsum,
                                                     int* __restrict__ rowptr,
                                                     unsigned* __restrict__ bases) {
    __shared__ unsigned ts[256];
    __shared__ unsigned pb[SCAN_NB];
    const int b = blockIdx.x, t = threadIdx.x;
    for (int i = t; i < SCAN_NB; i += 256) pb[i] = bsum[i];
    __syncthreads();
    if (t == 0) {           // redundant per-block exclusive scan of 391 chunk sums
        unsigned run = 0;
        for (int i = 0; i < SCAN_NB; i++) { unsigned x = pb[i]; pb[i] = run; run += x; }
    }
    __syncthreads();
    const int node = b * 256 + t;
    unsigned si = 0;
    if (node < N_NODES) {
        const int rg2 = node / RANGE2;
        const int wo = (node % RANGE2) >> 1;
        const int sh = (node & 1) << 4;
        const unsigned* pd = count2 + ((size_t)(NR2 + rg2) * GH) * R2W + wo;
        for (int g = 0; g < GH; g++) si += (pd[(size_t)g * R2W] >> sh) & 0xffffu;
    }
    ts[t] = si; __syncthreads();
    for (int off = 1; off < 256; off <<= 1) {
        unsigned add = (t >= off) ? ts[t - off] : 0u;
        __syncthreads();
        ts[t] += add;
        __syncthreads();
    }
    unsigned excl = (t == 0) ? 0u : ts[t - 1];
    unsigned run = pb[b] + excl;
    if (node < N_NODES) {
        rowptr[node] = (int)run;
        const int rg2 = node / RANGE2;
        const int wo = (node % RANGE2) >> 1;
        const int sh = (node & 1) << 4;
        const int rgS = node / RS;
        const int offS = node % RS;
        const unsigned* pd = count2 + ((size_t)(NR2 + rg2) * GH) * R2W + wo;
        unsigned* pb8 = bases + ((size_t)rgS * GH) * RS + offS;
        unsigned nrun = run;
        for (int g = 0; g < GH; g++) {
            unsigned c = (pd[(size_t)g * R2W] >> sh) & 0xffffu;
            pb8[(size_t)g * RS] = nrun;
            nrun += c;
        }
    }
    if (b == 0 && t == 0) rowptr[N_NODES] = N_EDGES;
}

// ---------------- sc_gemm1: scatter2 (blocks < NSC) MERGED with gemm1 (blocks >= NSC) ----
// Independent work co-scheduled in one launch: scatter2 is LDS-atomic-bound, gemm1 is
// HBM/MFMA-bound; their ~15us and ~50us overlap instead of serializing. Both fit a
// 50KB shared-LDS union -> gemm1 keeps 3 blocks/CU. Disjoint outputs (esrc vs H).
__global__ __launch_bounds__(256) void sc_gemm1(const int* __restrict__ src,
                                                const int* __restrict__ dst,
                                                const unsigned* __restrict__ bases,
                                                int* __restrict__ esrc,
                                                const float* __restrict__ X,
                                                const unsigned short* __restrict__ Wt,
                                                const float* __restrict__ nsrc,
                                                unsigned short* __restrict__ H) {
    __shared__ __align__(16) char smem[51200];   // 50KB union
    const int t = threadIdx.x;
    if (blockIdx.x < NSC) {
        // ---------- scatter2: CSR slot assignment via LDS cursors ----------
        unsigned* cur = (unsigned*)smem;         // 50KB
        const int rg = blockIdx.x / GH;
        const int g = blockIdx.x % GH;
        const int lo = rg * RS;
        const unsigned* base = bases + ((size_t)rg * GH + g) * RS;
        for (int i = t; i < RS; i += 256) cur[i] = base[i];
        __syncthreads();
        const int4* pd = (const int4*)(dst + g * EDGE_SLICE);
        const int4* ps = (const int4*)(src + g * EDGE_SLICE);
        for (int i = t; i < EDGE_SLICE / 4; i += 256) {
            int4 d4 = pd[i];
            int4 s4 = ps[i];
            int x;
            x = d4.x - lo; if ((unsigned)x < RS) esrc[atomicAdd(&cur[x], 1u)] = s4.x;
            x = d4.y - lo; if ((unsigned)x < RS) esrc[atomicAdd(&cur[x], 1u)] = s4.y;
            x = d4.z - lo; if ((unsigned)x < RS) esrc[atomicAdd(&cur[x], 1u)] = s4.z;
            x = d4.w - lo; if ((unsigned)x < RS) esrc[atomicAdd(&cur[x], 1u)] = s4.w;
        }
        return;
    }
    // ---------- gemm1 (bf16 MFMA, BK=128): H = nsrc * (bf16(X) @ bf16(W1)) ----------
    unsigned short* Bs = (unsigned short*)smem;            // 32KB [col][k]
    unsigned short* Xs = (unsigned short*)(smem + 32768);  // 16KB [row][k]
    const int bm = (blockIdx.x - NSC) * 64;
    const int w = t >> 6;
    const int l = t & 63;
    const int r = l & 15;
    const int kg = l >> 4;

    f32x4 acc[8];
#pragma unroll
    for (int c = 0; c < 8; c++) acc[c] = (f32x4){0.f, 0.f, 0.f, 0.f};

    for (int s = 0; s < FIN / 128; ++s) {
        const int k0 = s * 128;
        // B staging: 32 chunks of 1KB (chunk c -> cols c*4..c*4+3), 8 gloads/wave.
#pragma unroll
        for (int i = 0; i < 8; i++) {
            int c = i * 4 + w;
            int col = c * 4 + (l >> 4);
            int slotp = l & 15;
            gload_lds16(Wt + (size_t)col * FIN + k0 + ((slotp ^ (col & 15)) * 8),
                        Bs + c * 512);
        }
        // X staging (manual, fp32->bf16): 1024 tasks (row 0..63, slot 0..15), 4/thread
#pragma unroll
        for (int i = 0; i < 4; i++) {
            int idx = t + i * 256;
            int row = idx >> 4;
            int slot = idx & 15;
            int grow = bm + row;
            uint4 packed = make_uint4(0u, 0u, 0u, 0u);
            if (grow < N_NODES) {
                const float4* p = (const float4*)(X + (size_t)grow * FIN + k0 + slot * 8);
                float4 v0 = p[0];
                float4 v1 = p[1];
                packed.x = pk2bf(v0.x, v0.y);
                packed.y = pk2bf(v0.z, v0.w);
                packed.z = pk2bf(v1.x, v1.y);
                packed.w = pk2bf(v1.z, v1.w);
            }
            *(uint4*)&Xs[row * 128 + ((slot ^ (row & 15)) * 8)] = packed;
        }
        __syncthreads();
        const int arow = w * 16 + r;
#pragma unroll
        for (int ks = 0; ks < 4; ks++) {
            short8 a = *(const short8*)&Xs[arow * 128 + (((ks * 4 + kg) ^ r) * 8)];
#pragma unroll
            for (int c = 0; c < 8; c++) {
                const int brow = c * 16 + r;
                short8 b = *(const short8*)&Bs[brow * 128 + (((ks * 4 + kg) ^ r) * 8)];
                acc[c] = __builtin_amdgcn_mfma_f32_16x16x32_bf16(a, b, acc[c], 0, 0, 0);
            }
        }
        __syncthreads();
    }
    // epilogue: scale by nsrc[row], store bf16. C/D: col=lane&15, row=(lane>>4)*4+reg
#pragma unroll
    for (int j = 0; j < 4; j++) {
        int grow = bm + w * 16 + kg * 4 + j;
        if (grow < N_NODES) {
            float sc = nsrc[grow];
#pragma unroll
            for (int c = 0; c < 8; c++)
                H[(size_t)grow * FHID + c * 16 + r] = bf1(acc[c][j] * sc);
        }
    }
}

// ---------------- SpMM1 gather (bf16 H) + finish1: X2 = relu(ndst*sum H[src] + b1), bf16 out ----
// ONE NODE PER WAVE; unroll-8 (unroll-16 measured null -> L3-BW-bound).
__global__ __launch_bounds__(256) void spmm1_gather(const int* __restrict__ rowptr,
                                                    const int* __restrict__ esrc,
                                                    const unsigned* __restrict__ H,   // bf16x2
                                                    const float* __restrict__ ndst,
                                                    const float* __restrict__ b1,
                                                    unsigned* __restrict__ X2) {      // bf16x2
    int node = blockIdx.x * (blockDim.x >> 6) + (threadIdx.x >> 6);
    if (node >= N_NODES) return;
    int lane = threadIdx.x & 63;
    int beg = rowptr[node], end = rowptr[node + 1];
    float2 a0 = make_float2(0.f, 0.f), a1 = make_float2(0.f, 0.f);
    float2 a2 = make_float2(0.f, 0.f), a3 = make_float2(0.f, 0.f);
    int p = beg;
    for (; p + 7 < end; p += 8) {
        int s0 = esrc[p],     s1 = esrc[p + 1], s2 = esrc[p + 2], s3 = esrc[p + 3];
        int s4 = esrc[p + 4], s5 = esrc[p + 5], s6 = esrc[p + 6], s7 = esrc[p + 7];
        unsigned u0 = H[(size_t)s0 * (FHID / 2) + lane];
        unsigned u1 = H[(size_t)s1 * (FHID / 2) + lane];
        unsigned u2 = H[(size_t)s2 * (FHID / 2) + lane];
        unsigned u3 = H[(size_t)s3 * (FHID / 2) + lane];
        unsigned u4 = H[(size_t)s4 * (FHID / 2) + lane];
        unsigned u5 = H[(size_t)s5 * (FHID / 2) + lane];
        unsigned u6 = H[(size_t)s6 * (FHID / 2) + lane];
        unsigned u7 = H[(size_t)s7 * (FHID / 2) + lane];
        a0.x += __uint_as_float(u0 << 16) + __uint_as_float(u1 << 16);
        a0.y += __uint_as_float(u0 & 0xffff0000u) + __uint_as_float(u1 & 0xffff0000u);
        a1.x += __uint_as_float(u2 << 16) + __uint_as_float(u3 << 16);
        a1.y += __uint_as_float(u2 & 0xffff0000u) + __uint_as_float(u3 & 0xffff0000u);
        a2.x += __uint_as_float(u4 << 16) + __uint_as_float(u5 << 16);
        a2.y += __uint_as_float(u4 & 0xffff0000u) + __uint_as_float(u5 & 0xffff0000u);
        a3.x += __uint_as_float(u6 << 16) + __uint_as_float(u7 << 16);
        a3.y += __uint_as_float(u6 & 0xffff0000u) + __uint_as_float(u7 & 0xffff0000u);
    }
    for (; p + 1 < end; p += 2) {
        int s0 = esrc[p], s1 = esrc[p + 1];
        unsigned u0 = H[(size_t)s0 * (FHID / 2) + lane];
        unsigned u1 = H[(size_t)s1 * (FHID / 2) + lane];
        a0.x += __uint_as_float(u0 << 16) + __uint_as_float(u1 << 16);
        a0.y += __uint_as_float(u0 & 0xffff0000u) + __uint_as_float(u1 & 0xffff0000u);
    }
    if (p < end) {
        int s0 = esrc[p];
        unsigned u0 = H[(size_t)s0 * (FHID / 2) + lane];
        a1.x += __uint_as_float(u0 << 16);
        a1.y += __uint_as_float(u0 & 0xffff0000u);
    }
    float ax = (a0.x + a1.x) + (a2.x + a3.x);
    float ay = (a0.y + a1.y) + (a2.y + a3.y);
    float nd = ndst[node];
    float2 b = *(const float2*)(b1 + lane * 2);
    float ox = fmaxf(fmaf(ax, nd, b.x), 0.f);
    float oy = fmaxf(fmaf(ay, nd, b.y), 0.f);
    X2[(size_t)node * (FHID / 2) + lane] = pk2bf(ox, oy);
}

// ---------------- GEMM2 (bf16 MFMA, single-shot K=128): H2 = nsrc * (X2 @ W2), bf16 out ----
__global__ __launch_bounds__(256) void gemm2_mfma(const unsigned short* __restrict__ X2,  // bf16
                                                  const unsigned short* __restrict__ W2t,
                                                  const float* __restrict__ nsrc,
                                                  unsigned short* __restrict__ H2) {
    __shared__ __align__(16) unsigned short Xs[64 * 128];    // 16KB
    __shared__ __align__(16) unsigned short Bs[FOUTP * 128]; // 12KB
    const int t = threadIdx.x;
    const int bm = blockIdx.x * 64;
    const int w = t >> 6;
    const int l = t & 63;
    const int r = l & 15;
    const int kg = l >> 4;

    // X2 staging: async; chunk c -> rows c*4..c*4+3; global src pre-swizzled
#pragma unroll
    for (int i = 0; i < 4; i++) {
        int c = i * 4 + w;
        int row = c * 4 + (l >> 4);
        int slotp = l & 15;
        size_t grow = (size_t)(bm + row);
        if (grow >= N_NODES) grow = N_NODES - 1;   // clamp: stay in valid memory
        gload_lds16(X2 + grow * FHID + ((slotp ^ (row & 15)) * 8), Xs + c * 512);
    }
    // W2t staging: 12 chunks of 1KB
#pragma unroll
    for (int i = 0; i < 3; i++) {
        int c = i * 4 + w;
        int row = c * 4 + (l >> 4);
        int slotp = l & 15;
        gload_lds16(W2t + row * FHID + ((slotp ^ (row & 15)) * 8), Bs + c * 512);
    }
    __syncthreads();

    f32x4 acc[3];
#pragma unroll
    for (int c = 0; c < 3; c++) acc[c] = (f32x4){0.f, 0.f, 0.f, 0.f};
    const int arow = w * 16 + r;
#pragma unroll
    for (int ks = 0; ks < 4; ks++) {
        short8 a = *(const short8*)&Xs[arow * 128 + (((ks * 4 + kg) ^ r) * 8)];
#pragma unroll
        for (int c = 0; c < 3; c++) {
            short8 b = *(const short8*)&Bs[(c * 16 + r) * 128 + (((ks * 4 + kg) ^ r) * 8)];
            acc[c] = __builtin_amdgcn_mfma_f32_16x16x32_bf16(a, b, acc[c], 0, 0, 0);
        }
    }
#pragma unroll
    for (int j = 0; j < 4; j++) {
        int grow = bm + w * 16 + kg * 4 + j;
        if (grow < N_NODES) {
            float sc = nsrc[grow];
#pragma unroll
            for (int c = 0; c < 3; c++) {
                int col = c * 16 + r;
                if (col < FOUT)
                    H2[(size_t)grow * FOUT + col] = bf1(acc[c][j] * sc);
            }
        }
    }
}

// ---------------- SpMM2 gather (bf16 H2) + finish2: OUT = ndst * sum H2[src] + b2 ----
// 3 nodes per wave (lane = sub*20 + feat); unroll-4.
__global__ __launch_bounds__(256) void spmm2_gather(const int* __restrict__ rowptr,
                                                    const int* __restrict__ esrc,
                                                    const unsigned* __restrict__ H2,  // bf16x2, 20 u32/row
                                                    const float* __restrict__ ndst,
                                                    const float* __restrict__ b2,
                                                    float* __restrict__ OUT) {
    const int wave = (threadIdx.x >> 6);
    const int lane = threadIdx.x & 63;
    const int sub = lane / 20;            // 0..2 (3 for lanes 60..63)
    const int feat = lane % 20;
    int node = blockIdx.x * 12 + wave * 3 + sub;
    if (sub >= 3 || node >= N_NODES) return;
    int beg = rowptr[node], end = rowptr[node + 1];
    float2 a0 = make_float2(0.f, 0.f), a1 = make_float2(0.f, 0.f);
    float2 a2 = make_float2(0.f, 0.f), a3 = make_float2(0.f, 0.f);
    int p = beg;
    for (; p + 3 < end; p += 4) {
        int s0 = esrc[p], s1 = esrc[p + 1], s2 = esrc[p + 2], s3 = esrc[p + 3];
        unsigned u0 = H2[(size_t)s0 * (FOUT / 2) + feat];
        unsigned u1 = H2[(size_t)s1 * (FOUT / 2) + feat];
        unsigned u2 = H2[(size_t)s2 * (FOUT / 2) + feat];
        unsigned u3 = H2[(size_t)s3 * (FOUT / 2) + feat];
        a0.x += __uint_as_float(u0 << 16);
        a0.y += __uint_as_float(u0 & 0xffff0000u);
        a1.x += __uint_as_float(u1 << 16);
        a1.y += __uint_as_float(u1 & 0xffff0000u);
        a2.x += __uint_as_float(u2 << 16);
        a2.y += __uint_as_float(u2 & 0xffff0000u);
        a3.x += __uint_as_float(u3 << 16);
        a3.y += __uint_as_float(u3 & 0xffff0000u);
    }
    for (; p < end; ++p) {
        int s0 = esrc[p];
        unsigned u0 = H2[(size_t)s0 * (FOUT / 2) + feat];
        a0.x += __uint_as_float(u0 << 16);
        a0.y += __uint_as_float(u0 & 0xffff0000u);
    }
    float ax = (a0.x + a1.x) + (a2.x + a3.x);
    float ay = (a0.y + a1.y) + (a2.y + a3.y);
    float nd = ndst[node];
    float2 b = *(const float2*)(b2 + feat * 2);
    float2 o;
    o.x = fmaf(ax, nd, b.x);
    o.y = fmaf(ay, nd, b.y);
    *(float2*)(OUT + (size_t)node * FOUT + feat * 2) = o;
}

extern "C" void kernel_launch(void* const* d_in, const int* in_sizes, int n_in,
                              void* d_out, int out_size, void* d_ws, size_t ws_size,
                              hipStream_t stream) {
    const float* feat = (const float*)d_in[0];
    const int*   src  = (const int*)d_in[1];
    const int*   dst  = (const int*)d_in[2];
    const float* W1   = (const float*)d_in[3];
    const float* b1   = (const float*)d_in[4];
    const float* W2   = (const float*)d_in[5];
    const float* b2   = (const float*)d_in[6];
    float* out = (float*)d_out;

    char* ws = (char*)d_ws;
    const size_t SZ_BIG = (size_t)N_NODES * FHID * sizeof(float);   // 51.2 MB
    const size_t SZ_CNT = (size_t)2 * NR2 * GH * R2W * 4;           // 25.6 MB
    // Layout (temporally disjoint overlaps):
    //  [0, 25.6MB)                    Hbf    (bf16 H, gemm1 out)
    //  [SZ_BIG, +25.6MB)              count2 (dead after scan_write_mk) / X2bf (spmm1 out)
    //  [SZ_BIG+25.6MB, +25.6MB)       bases  (dead after sc_gemm1)
    //  [SZ_BIG+26MB, +8MB)            H2bf   (gemm2 out; written after bases dead)
    unsigned short* Hbf    = (unsigned short*)ws;
    unsigned*       count2 = (unsigned*)(ws + SZ_BIG);
    unsigned*       bases  = (unsigned*)(ws + SZ_BIG + SZ_CNT);
    unsigned short* X2bf   = (unsigned short*)(ws + SZ_BIG);
    unsigned short* H2bf   = (unsigned short*)(ws + SZ_BIG + (26u << 20));
    char* small = ws + 2 * SZ_BIG;
    const size_t SSTRIDE = 401408;                  // 512B-aligned
    float*    nsrc   = (float*)(small);
    float*    ndst   = (float*)(small + SSTRIDE);
    int*      rowptr = (int*)(small + 2 * SSTRIDE);
    unsigned* bsum   = (unsigned*)(small + 3 * SSTRIDE);
    unsigned short* Wt  = (unsigned short*)(small + 4 * SSTRIDE);            // 128KB bf16 W1^T
    unsigned short* W2t = (unsigned short*)(small + 4 * SSTRIDE + 131072);   // 12KB bf16 W2^T padded
    int*      esrc   = (int*)(small + 5 * SSTRIDE);                          // 6.4 MB

    // CSR build + weight conversion (no global atomics, no memset needed)
    const int NWCVT = (FIN * FHID + FOUTP * FHID + 255) / 256;   // 280
    hist_wcvt<<<NHIST + NWCVT, 256, 0, stream>>>(src, dst, count2, W1, W2, Wt, W2t);
    deg_reduce_scan<<<SCAN_NB, 256, 0, stream>>>(count2, nsrc, ndst, bsum);
    scan_write_mk<<<SCAN_NB, 256, 0, stream>>>(count2, bsum, rowptr, bases);

    // scatter2 (LDS-atomic-bound) co-scheduled with gemm1 (HBM/MFMA-bound): both
    // depend only on {bases} / {Wt, nsrc}, all ready; outputs disjoint (esrc vs H).
    sc_gemm1<<<NSC + (N_NODES + 63) / 64, 256, 0, stream>>>(src, dst, bases, esrc,
                                                            feat, Wt, nsrc, Hbf);

    spmm1_gather<<<(N_NODES + 3) / 4, 256, 0, stream>>>(rowptr, esrc, (const unsigned*)Hbf,
                                                        ndst, b1, (unsigned*)X2bf);   // count2 dead
    gemm2_mfma<<<(N_NODES + 63) / 64, 256, 0, stream>>>(X2bf, W2t, nsrc, H2bf);       // bases dead
    spmm2_gather<<<(N_NODES + 11) / 12, 256, 0, stream>>>(rowptr, esrc, (const unsigned*)H2bf,
                                                          ndst, b2, out);
}

// Round 15
// 238.583 us; speedup vs baseline: 1.0247x; 1.0247x over previous
//
#include <hip/hip_runtime.h>
#include <hip/hip_bf16.h>

#define N_NODES 100000
#define N_EDGES 1600000
#define FIN 512
#define FHID 128
#define FOUT 40
#define FOUTP 48                // FOUT padded to 3x16 for MFMA

#define SCAN_NB ((N_NODES + 255) / 256)   // 391 blocks, 1 node/thread

// scatter geometry (u32 cursors in 50KB LDS)
#define NRANGE 8
#define RANGE_SZ 12500
#define GH 64                   // edge slices (512 blocks = 2/CU)
#define EDGE_SLICE (N_EDGES / GH)   // 25000

// histogram geometry (u16-packed pairs in 50KB LDS)
#define NR4 4
#define RANGE2 25000
#define R2WORDS 12500
#define NHIST (2 * NR4 * GH)    // 512 histogram blocks

typedef __attribute__((ext_vector_type(8))) short short8;   // 8 bf16 (4 VGPR)
typedef __attribute__((ext_vector_type(4))) float f32x4;    // MFMA acc

static __device__ inline unsigned short f2bf(float f) {     // cold paths only
    unsigned x = __float_as_uint(f);
    unsigned r = (x + 0x7fffu + ((x >> 16) & 1u)) >> 16;    // RNE
    return (unsigned short)r;
}

// hot-path pair conversion -> v_cvt_pk_bf16_f32 (compiler-emitted)
static __device__ inline unsigned pk2bf(float lo, float hi) {
    __hip_bfloat162 h = __float22bfloat162_rn(make_float2(lo, hi));
    return *(unsigned*)&h;
}
static __device__ inline unsigned short bf1(float f) {
    __hip_bfloat16 h = __float2bfloat16(f);
    return *(unsigned short*)&h;
}

// async global->LDS 16B copy: LDS dest = wave-uniform base + lane*16 (linear);
// swizzling achieved by pre-swizzling the per-lane GLOBAL source address.
static __device__ inline void gload_lds16(const unsigned short* g, unsigned short* l) {
    __builtin_amdgcn_global_load_lds(
        (const __attribute__((address_space(1))) unsigned int*)(g),
        (__attribute__((address_space(3))) unsigned int*)(l), 16, 0, 0);
}

// ---------------- hist_wcvt: u16-packed LDS degree histograms + weight conversion ----
// Blocks [0, NHIST): histogram task (a,rg4,g). Blocks >= NHIST: weight bf16 transpose.
__global__ __launch_bounds__(256) void hist_wcvt(const int* __restrict__ src,
                                                 const int* __restrict__ dst,
                                                 unsigned* __restrict__ count2,
                                                 const float* __restrict__ W1,
                                                 const float* __restrict__ W2,
                                                 unsigned short* __restrict__ Wt,
                                                 unsigned short* __restrict__ W2t) {
    __shared__ unsigned hist[R2WORDS];   // 50KB (unused by wcvt blocks)
    if (blockIdx.x >= NHIST) {
        int j = (blockIdx.x - NHIST) * 256 + threadIdx.x;
        if (j < FIN * FHID) {             // Wt[n][k] = bf16(W1[k][n]); j = k*128+n
            int k = j >> 7;
            int n = j & 127;
            Wt[n * FIN + k] = f2bf(W1[j]);
        } else if (j < FIN * FHID + FOUTP * FHID) {
            int jj = j - FIN * FHID;      // W2t[n][k]; jj = n*128+k
            int n = jj >> 7;
            int k = jj & 127;
            W2t[jj] = (n < FOUT) ? f2bf(W2[k * FOUT + n]) : (unsigned short)0;
        }
        return;
    }
    const int task = blockIdx.x / GH;
    const int g = blockIdx.x % GH;
    const int a = task / NR4;
    const int rg = task % NR4;
    const int lo = rg * RANGE2;
    const int t = threadIdx.x;
    for (int i = t; i < R2WORDS; i += 256) hist[i] = 0;
    __syncthreads();
    const int* arr = a ? dst : src;
    const int4* p = (const int4*)(arr + g * EDGE_SLICE);
    for (int i = t; i < EDGE_SLICE / 4; i += 256) {
        int4 v = p[i];
        int x;
        x = v.x - lo; if ((unsigned)x < RANGE2) atomicAdd(&hist[x >> 1], 1u << ((x & 1) << 4));
        x = v.y - lo; if ((unsigned)x < RANGE2) atomicAdd(&hist[x >> 1], 1u << ((x & 1) << 4));
        x = v.z - lo; if ((unsigned)x < RANGE2) atomicAdd(&hist[x >> 1], 1u << ((x & 1) << 4));
        x = v.w - lo; if ((unsigned)x < RANGE2) atomicAdd(&hist[x >> 1], 1u << ((x & 1) << 4));
    }
    __syncthreads();
    unsigned* out = count2 + ((size_t)task * GH + g) * R2WORDS;
    for (int i = t; i < R2WORDS; i += 256) out[i] = hist[i];
}

// ---------------- deg_reduce_scan: norms + per-256-chunk degree sums ----------------
// 391 blocks, 1 node/thread.
__global__ __launch_bounds__(256) void deg_reduce_scan(const unsigned* __restrict__ count2,
                                                       float* __restrict__ nsrc,
                                                       float* __restrict__ ndst,
                                                       unsigned* __restrict__ bsum) {
    __shared__ unsigned red[256];
    const int b = blockIdx.x, t = threadIdx.x;
    const int node = b * 256 + t;
    unsigned si = 0;
    if (node < N_NODES) {
        const int rg4 = node / RANGE2;
        const int wo = (node % RANGE2) >> 1;
        const int sh = (node & 1) << 4;
        const unsigned* ps = count2 + ((size_t)rg4 * GH) * R2WORDS + wo;
        const unsigned* pd = count2 + ((size_t)(NR4 + rg4) * GH) * R2WORDS + wo;
        unsigned so = 0;
        for (int g = 0; g < GH; g++) {
            so += (ps[(size_t)g * R2WORDS] >> sh) & 0xffffu;
            si += (pd[(size_t)g * R2WORDS] >> sh) & 0xffffu;
        }
        nsrc[node] = rsqrtf((float)(so < 1u ? 1u : so));
        ndst[node] = rsqrtf((float)(si < 1u ? 1u : si));
    }
    red[t] = si; __syncthreads();
    for (int off = 128; off > 0; off >>= 1) {
        if (t < off) red[t] += red[t + off];
        __syncthreads();
    }
    if (t == 0) bsum[b] = red[0];
}

// ---------------- scan_write_mk: bsum-prefix + rowptr + u32 scatter bases (fused) ----
// 391 blocks, 1 node/thread.
__global__ __launch_bounds__(256) void scan_write_mk(const unsigned* __restrict__ count2,
                                                     const unsigned* __restrict__ bsum,
                                                     int* __restrict__ rowptr,
                                                     unsigned* __restrict__ bases) {
    __shared__ unsigned ts[256];
    __shared__ unsigned pb[SCAN_NB];
    const int b = blockIdx.x, t = threadIdx.x;
    for (int i = t; i < SCAN_NB; i += 256) pb[i] = bsum[i];
    __syncthreads();
    if (t == 0) {           // redundant per-block exclusive scan of 391 chunk sums
        unsigned run = 0;
        for (int i = 0; i < SCAN_NB; i++) { unsigned x = pb[i]; pb[i] = run; run += x; }
    }
    __syncthreads();
    const int node = b * 256 + t;
    unsigned si = 0;
    if (node < N_NODES) {
        const int rg4 = node / RANGE2;
        const int wo = (node % RANGE2) >> 1;
        const int sh = (node & 1) << 4;
        const unsigned* pd = count2 + ((size_t)(NR4 + rg4) * GH) * R2WORDS + wo;
        for (int g = 0; g < GH; g++) si += (pd[(size_t)g * R2WORDS] >> sh) & 0xffffu;
    }
    ts[t] = si; __syncthreads();
    for (int off = 1; off < 256; off <<= 1) {
        unsigned add = (t >= off) ? ts[t - off] : 0u;
        __syncthreads();
        ts[t] += add;
        __syncthreads();
    }
    unsigned excl = (t == 0) ? 0u : ts[t - 1];
    unsigned run = pb[b] + excl;
    if (node < N_NODES) {
        rowptr[node] = (int)run;
        const int rg4 = node / RANGE2;
        const int wo = (node % RANGE2) >> 1;
        const int sh = (node & 1) << 4;
        const int rg8 = node / RANGE_SZ;
        const int off8 = node % RANGE_SZ;
        const unsigned* pd = count2 + ((size_t)(NR4 + rg4) * GH) * R2WORDS + wo;
        unsigned* pb8 = bases + ((size_t)rg8 * GH) * RANGE_SZ + off8;
        unsigned nrun = run;
        for (int g = 0; g < GH; g++) {
            unsigned c = (pd[(size_t)g * R2WORDS] >> sh) & 0xffffu;
            pb8[(size_t)g * RANGE_SZ] = nrun;
            nrun += c;
        }
    }
    if (b == 0 && t == 0) rowptr[N_NODES] = N_EDGES;
}

// ---------------- scatter2: CSR slot assignment via LDS cursors only ----------------
__global__ __launch_bounds__(256) void scatter2(const int* __restrict__ src,
                                                const int* __restrict__ dst,
                                                const unsigned* __restrict__ bases,
                                                int* __restrict__ esrc) {
    __shared__ unsigned cur[RANGE_SZ];   // 50KB
    const int rg = blockIdx.x / GH;
    const int g = blockIdx.x % GH;
    const int lo = rg * RANGE_SZ;
    const int t = threadIdx.x;
    const unsigned* base = bases + ((size_t)rg * GH + g) * RANGE_SZ;
    for (int i = t; i < RANGE_SZ; i += 256) cur[i] = base[i];
    __syncthreads();
    const int4* pd = (const int4*)(dst + g * EDGE_SLICE);
    const int4* ps = (const int4*)(src + g * EDGE_SLICE);
    for (int i = t; i < EDGE_SLICE / 4; i += 256) {
        int4 d4 = pd[i];
        int4 s4 = ps[i];
        int x;
        x = d4.x - lo; if ((unsigned)x < RANGE_SZ) esrc[atomicAdd(&cur[x], 1u)] = s4.x;
        x = d4.y - lo; if ((unsigned)x < RANGE_SZ) esrc[atomicAdd(&cur[x], 1u)] = s4.y;
        x = d4.z - lo; if ((unsigned)x < RANGE_SZ) esrc[atomicAdd(&cur[x], 1u)] = s4.z;
        x = d4.w - lo; if ((unsigned)x < RANGE_SZ) esrc[atomicAdd(&cur[x], 1u)] = s4.w;
    }
}

// ---------------- GEMM1 (bf16 MFMA, BK=128): H = nsrc * (bf16(X) @ bf16(W1)), bf16 out ----
__global__ __launch_bounds__(256) void gemm1_mfma(const float* __restrict__ X,
                                                  const unsigned short* __restrict__ Wt,
                                                  const float* __restrict__ nsrc,
                                                  unsigned short* __restrict__ H) {
    __shared__ __align__(16) unsigned short Xs[64 * 128];    // 16KB [row][k], 16 slots/row
    __shared__ __align__(16) unsigned short Bs[128 * 128];   // 32KB [col][k]
    const int t = threadIdx.x;
    const int bm = blockIdx.x * 64;
    const int w = t >> 6;
    const int l = t & 63;
    const int r = l & 15;
    const int kg = l >> 4;

    f32x4 acc[8];
#pragma unroll
    for (int c = 0; c < 8; c++) acc[c] = (f32x4){0.f, 0.f, 0.f, 0.f};

    for (int s = 0; s < FIN / 128; ++s) {
        const int k0 = s * 128;
        // B staging: 32 chunks of 1KB (chunk c -> cols c*4..c*4+3), 8 gloads/wave.
#pragma unroll
        for (int i = 0; i < 8; i++) {
            int c = i * 4 + w;
            int col = c * 4 + (l >> 4);
            int slotp = l & 15;
            gload_lds16(Wt + (size_t)col * FIN + k0 + ((slotp ^ (col & 15)) * 8),
                        Bs + c * 512);
        }
        // X staging (manual, fp32->bf16): 1024 tasks (row 0..63, slot 0..15), 4/thread
#pragma unroll
        for (int i = 0; i < 4; i++) {
            int idx = t + i * 256;
            int row = idx >> 4;
            int slot = idx & 15;
            int grow = bm + row;
            uint4 packed = make_uint4(0u, 0u, 0u, 0u);
            if (grow < N_NODES) {
                const float4* p = (const float4*)(X + (size_t)grow * FIN + k0 + slot * 8);
                float4 v0 = p[0];
                float4 v1 = p[1];
                packed.x = pk2bf(v0.x, v0.y);
                packed.y = pk2bf(v0.z, v0.w);
                packed.z = pk2bf(v1.x, v1.y);
                packed.w = pk2bf(v1.z, v1.w);
            }
            *(uint4*)&Xs[row * 128 + ((slot ^ (row & 15)) * 8)] = packed;
        }
        __syncthreads();
        const int arow = w * 16 + r;
#pragma unroll
        for (int ks = 0; ks < 4; ks++) {
            short8 a = *(const short8*)&Xs[arow * 128 + (((ks * 4 + kg) ^ r) * 8)];
#pragma unroll
            for (int c = 0; c < 8; c++) {
                const int brow = c * 16 + r;
                short8 b = *(const short8*)&Bs[brow * 128 + (((ks * 4 + kg) ^ r) * 8)];
                acc[c] = __builtin_amdgcn_mfma_f32_16x16x32_bf16(a, b, acc[c], 0, 0, 0);
            }
        }
        __syncthreads();
    }
    // epilogue: scale by nsrc[row], store bf16. C/D: col=lane&15, row=(lane>>4)*4+reg
#pragma unroll
    for (int j = 0; j < 4; j++) {
        int grow = bm + w * 16 + kg * 4 + j;
        if (grow < N_NODES) {
            float sc = nsrc[grow];
#pragma unroll
            for (int c = 0; c < 8; c++)
                H[(size_t)grow * FHID + c * 16 + r] = bf1(acc[c][j] * sc);
        }
    }
}

// ---------------- SpMM1 gather (bf16 H) + finish1: X2 = relu(ndst*sum H[src] + b1), bf16 out ----
// ONE NODE PER WAVE; unroll-8 (unroll-16 measured null -> L3-BW-bound).
__global__ __launch_bounds__(256) void spmm1_gather(const int* __restrict__ rowptr,
                                                    const int* __restrict__ esrc,
                                                    const unsigned* __restrict__ H,   // bf16x2
                                                    const float* __restrict__ ndst,
                                                    const float* __restrict__ b1,
                                                    unsigned* __restrict__ X2) {      // bf16x2
    int node = blockIdx.x * (blockDim.x >> 6) + (threadIdx.x >> 6);
    if (node >= N_NODES) return;
    int lane = threadIdx.x & 63;
    int beg = rowptr[node], end = rowptr[node + 1];
    float2 a0 = make_float2(0.f, 0.f), a1 = make_float2(0.f, 0.f);
    float2 a2 = make_float2(0.f, 0.f), a3 = make_float2(0.f, 0.f);
    int p = beg;
    for (; p + 7 < end; p += 8) {
        int s0 = esrc[p],     s1 = esrc[p + 1], s2 = esrc[p + 2], s3 = esrc[p + 3];
        int s4 = esrc[p + 4], s5 = esrc[p + 5], s6 = esrc[p + 6], s7 = esrc[p + 7];
        unsigned u0 = H[(size_t)s0 * (FHID / 2) + lane];
        unsigned u1 = H[(size_t)s1 * (FHID / 2) + lane];
        unsigned u2 = H[(size_t)s2 * (FHID / 2) + lane];
        unsigned u3 = H[(size_t)s3 * (FHID / 2) + lane];
        unsigned u4 = H[(size_t)s4 * (FHID / 2) + lane];
        unsigned u5 = H[(size_t)s5 * (FHID / 2) + lane];
        unsigned u6 = H[(size_t)s6 * (FHID / 2) + lane];
        unsigned u7 = H[(size_t)s7 * (FHID / 2) + lane];
        a0.x += __uint_as_float(u0 << 16) + __uint_as_float(u1 << 16);
        a0.y += __uint_as_float(u0 & 0xffff0000u) + __uint_as_float(u1 & 0xffff0000u);
        a1.x += __uint_as_float(u2 << 16) + __uint_as_float(u3 << 16);
        a1.y += __uint_as_float(u2 & 0xffff0000u) + __uint_as_float(u3 & 0xffff0000u);
        a2.x += __uint_as_float(u4 << 16) + __uint_as_float(u5 << 16);
        a2.y += __uint_as_float(u4 & 0xffff0000u) + __uint_as_float(u5 & 0xffff0000u);
        a3.x += __uint_as_float(u6 << 16) + __uint_as_float(u7 << 16);
        a3.y += __uint_as_float(u6 & 0xffff0000u) + __uint_as_float(u7 & 0xffff0000u);
    }
    for (; p + 1 < end; p += 2) {
        int s0 = esrc[p], s1 = esrc[p + 1];
        unsigned u0 = H[(size_t)s0 * (FHID / 2) + lane];
        unsigned u1 = H[(size_t)s1 * (FHID / 2) + lane];
        a0.x += __uint_as_float(u0 << 16) + __uint_as_float(u1 << 16);
        a0.y += __uint_as_float(u0 & 0xffff0000u) + __uint_as_float(u1 & 0xffff0000u);
    }
    if (p < end) {
        int s0 = esrc[p];
        unsigned u0 = H[(size_t)s0 * (FHID / 2) + lane];
        a1.x += __uint_as_float(u0 << 16);
        a1.y += __uint_as_float(u0 & 0xffff0000u);
    }
    float ax = (a0.x + a1.x) + (a2.x + a3.x);
    float ay = (a0.y + a1.y) + (a2.y + a3.y);
    float nd = ndst[node];
    float2 b = *(const float2*)(b1 + lane * 2);
    float ox = fmaxf(fmaf(ax, nd, b.x), 0.f);
    float oy = fmaxf(fmaf(ay, nd, b.y), 0.f);
    X2[(size_t)node * (FHID / 2) + lane] = pk2bf(ox, oy);
}

// ---------------- GEMM2 (bf16 MFMA, single-shot K=128): H2 = nsrc * (X2 @ W2), bf16 out ----
__global__ __launch_bounds__(256) void gemm2_mfma(const unsigned short* __restrict__ X2,  // bf16
                                                  const unsigned short* __restrict__ W2t,
                                                  const float* __restrict__ nsrc,
                                                  unsigned short* __restrict__ H2) {
    __shared__ __align__(16) unsigned short Xs[64 * 128];    // 16KB
    __shared__ __align__(16) unsigned short Bs[FOUTP * 128]; // 12KB
    const int t = threadIdx.x;
    const int bm = blockIdx.x * 64;
    const int w = t >> 6;
    const int l = t & 63;
    const int r = l & 15;
    const int kg = l >> 4;

    // X2 staging: async; chunk c -> rows c*4..c*4+3; global src pre-swizzled
#pragma unroll
    for (int i = 0; i < 4; i++) {
        int c = i * 4 + w;
        int row = c * 4 + (l >> 4);
        int slotp = l & 15;
        size_t grow = (size_t)(bm + row);
        if (grow >= N_NODES) grow = N_NODES - 1;   // clamp: stay in valid memory
        gload_lds16(X2 + grow * FHID + ((slotp ^ (row & 15)) * 8), Xs + c * 512);
    }
    // W2t staging: 12 chunks of 1KB
#pragma unroll
    for (int i = 0; i < 3; i++) {
        int c = i * 4 + w;
        int row = c * 4 + (l >> 4);
        int slotp = l & 15;
        gload_lds16(W2t + row * FHID + ((slotp ^ (row & 15)) * 8), Bs + c * 512);
    }
    __syncthreads();

    f32x4 acc[3];
#pragma unroll
    for (int c = 0; c < 3; c++) acc[c] = (f32x4){0.f, 0.f, 0.f, 0.f};
    const int arow = w * 16 + r;
#pragma unroll
    for (int ks = 0; ks < 4; ks++) {
        short8 a = *(const short8*)&Xs[arow * 128 + (((ks * 4 + kg) ^ r) * 8)];
#pragma unroll
        for (int c = 0; c < 3; c++) {
            short8 b = *(const short8*)&Bs[(c * 16 + r) * 128 + (((ks * 4 + kg) ^ r) * 8)];
            acc[c] = __builtin_amdgcn_mfma_f32_16x16x32_bf16(a, b, acc[c], 0, 0, 0);
        }
    }
#pragma unroll
    for (int j = 0; j < 4; j++) {
        int grow = bm + w * 16 + kg * 4 + j;
        if (grow < N_NODES) {
            float sc = nsrc[grow];
#pragma unroll
            for (int c = 0; c < 3; c++) {
                int col = c * 16 + r;
                if (col < FOUT)
                    H2[(size_t)grow * FOUT + col] = bf1(acc[c][j] * sc);
            }
        }
    }
}

// ---------------- SpMM2 gather (bf16 H2) + finish2: OUT = ndst * sum H2[src] + b2 ----
// 3 nodes per wave (lane = sub*20 + feat); unroll-4.
__global__ __launch_bounds__(256) void spmm2_gather(const int* __restrict__ rowptr,
                                                    const int* __restrict__ esrc,
                                                    const unsigned* __restrict__ H2,  // bf16x2, 20 u32/row
                                                    const float* __restrict__ ndst,
                                                    const float* __restrict__ b2,
                                                    float* __restrict__ OUT) {
    const int wave = (threadIdx.x >> 6);
    const int lane = threadIdx.x & 63;
    const int sub = lane / 20;            // 0..2 (3 for lanes 60..63)
    const int feat = lane % 20;
    int node = blockIdx.x * 12 + wave * 3 + sub;
    if (sub >= 3 || node >= N_NODES) return;
    int beg = rowptr[node], end = rowptr[node + 1];
    float2 a0 = make_float2(0.f, 0.f), a1 = make_float2(0.f, 0.f);
    float2 a2 = make_float2(0.f, 0.f), a3 = make_float2(0.f, 0.f);
    int p = beg;
    for (; p + 3 < end; p += 4) {
        int s0 = esrc[p], s1 = esrc[p + 1], s2 = esrc[p + 2], s3 = esrc[p + 3];
        unsigned u0 = H2[(size_t)s0 * (FOUT / 2) + feat];
        unsigned u1 = H2[(size_t)s1 * (FOUT / 2) + feat];
        unsigned u2 = H2[(size_t)s2 * (FOUT / 2) + feat];
        unsigned u3 = H2[(size_t)s3 * (FOUT / 2) + feat];
        a0.x += __uint_as_float(u0 << 16);
        a0.y += __uint_as_float(u0 & 0xffff0000u);
        a1.x += __uint_as_float(u1 << 16);
        a1.y += __uint_as_float(u1 & 0xffff0000u);
        a2.x += __uint_as_float(u2 << 16);
        a2.y += __uint_as_float(u2 & 0xffff0000u);
        a3.x += __uint_as_float(u3 << 16);
        a3.y += __uint_as_float(u3 & 0xffff0000u);
    }
    for (; p < end; ++p) {
        int s0 = esrc[p];
        unsigned u0 = H2[(size_t)s0 * (FOUT / 2) + feat];
        a0.x += __uint_as_float(u0 << 16);
        a0.y += __uint_as_float(u0 & 0xffff0000u);
    }
    float ax = (a0.x + a1.x) + (a2.x + a3.x);
    float ay = (a0.y + a1.y) + (a2.y + a3.y);
    float nd = ndst[node];
    float2 b = *(const float2*)(b2 + feat * 2);
    float2 o;
    o.x = fmaf(ax, nd, b.x);
    o.y = fmaf(ay, nd, b.y);
    *(float2*)(OUT + (size_t)node * FOUT + feat * 2) = o;
}

extern "C" void kernel_launch(void* const* d_in, const int* in_sizes, int n_in,
                              void* d_out, int out_size, void* d_ws, size_t ws_size,
                              hipStream_t stream) {
    const float* feat = (const float*)d_in[0];
    const int*   src  = (const int*)d_in[1];
    const int*   dst  = (const int*)d_in[2];
    const float* W1   = (const float*)d_in[3];
    const float* b1   = (const float*)d_in[4];
    const float* W2   = (const float*)d_in[5];
    const float* b2   = (const float*)d_in[6];
    float* out = (float*)d_out;

    char* ws = (char*)d_ws;
    const size_t SZ_BIG = (size_t)N_NODES * FHID * sizeof(float);   // 51.2 MB
    const size_t SZ_CNT = (size_t)2 * NR4 * GH * R2WORDS * 4;       // 25.6 MB
    // Layout (temporally disjoint overlaps):
    //  [0, 25.6MB)                    Hbf    (bf16 H, gemm1 out)
    //  [SZ_BIG, +25.6MB)              count2 (dead after scan_write_mk) / X2bf (spmm1 out)
    //  [SZ_BIG+25.6MB, +25.6MB)       bases  (dead after scatter2)
    //  [SZ_BIG+26MB, +8MB)            H2bf   (gemm2 out; written after bases dead)
    unsigned short* Hbf    = (unsigned short*)ws;
    unsigned*       count2 = (unsigned*)(ws + SZ_BIG);
    unsigned*       bases  = (unsigned*)(ws + SZ_BIG + SZ_CNT);
    unsigned short* X2bf   = (unsigned short*)(ws + SZ_BIG);
    unsigned short* H2bf   = (unsigned short*)(ws + SZ_BIG + (26u << 20));
    char* small = ws + 2 * SZ_BIG;
    const size_t SSTRIDE = 401408;                  // 512B-aligned
    float*    nsrc   = (float*)(small);
    float*    ndst   = (float*)(small + SSTRIDE);
    int*      rowptr = (int*)(small + 2 * SSTRIDE);
    unsigned* bsum   = (unsigned*)(small + 3 * SSTRIDE);
    unsigned short* Wt  = (unsigned short*)(small + 4 * SSTRIDE);            // 128KB bf16 W1^T
    unsigned short* W2t = (unsigned short*)(small + 4 * SSTRIDE + 131072);   // 12KB bf16 W2^T padded
    int*      esrc   = (int*)(small + 5 * SSTRIDE);                          // 6.4 MB

    // CSR build + weight conversion (no global atomics, no memset needed)
    const int NWCVT = (FIN * FHID + FOUTP * FHID + 255) / 256;   // 280
    hist_wcvt<<<NHIST + NWCVT, 256, 0, stream>>>(src, dst, count2, W1, W2, Wt, W2t);
    deg_reduce_scan<<<SCAN_NB, 256, 0, stream>>>(count2, nsrc, ndst, bsum);
    scan_write_mk<<<SCAN_NB, 256, 0, stream>>>(count2, bsum, rowptr, bases);
    scatter2<<<NRANGE * GH, 256, 0, stream>>>(src, dst, bases, esrc);

    gemm1_mfma<<<(N_NODES + 63) / 64, 256, 0, stream>>>(feat, Wt, nsrc, Hbf);
    spmm1_gather<<<(N_NODES + 3) / 4, 256, 0, stream>>>(rowptr, esrc, (const unsigned*)Hbf,
                                                        ndst, b1, (unsigned*)X2bf);   // count2 dead
    gemm2_mfma<<<(N_NODES + 63) / 64, 256, 0, stream>>>(X2bf, W2t, nsrc, H2bf);       // bases dead
    spmm2_gather<<<(N_NODES + 11) / 12, 256, 0, stream>>>(rowptr, esrc, (const unsigned*)H2bf,
                                                          ndst, b2, out);
}